// Round 1
// baseline (382.828 us; speedup 1.0000x reference)
//
#include <hip/hip_runtime.h>
#include <math.h>

#define DMODEL 512
#define DINNER 1024
#define DTRANK 32
#define DSTATE 16
#define HW     16384   // 128*128
#define BATCH  8

// ---------------------------------------------------------------------------
// Kernel 1: mean over spatial dims. One block per (b,c) row of 16384 floats.
// ---------------------------------------------------------------------------
__global__ __launch_bounds__(256) void mean_kernel(const float* __restrict__ x,
                                                   float* __restrict__ mean_out) {
    const int row = blockIdx.x;                       // b*512 + c  (4096 rows)
    const float4* xr = (const float4*)(x + (size_t)row * HW);
    const int t = threadIdx.x;
    float s = 0.f;
#pragma unroll
    for (int j = 0; j < 16; ++j) {                    // 4096 float4 / 256 thr
        float4 v = xr[t + j * 256];
        s += v.x + v.y + v.z + v.w;
    }
    // wave-64 shuffle reduce
    for (int off = 32; off; off >>= 1) s += __shfl_down(s, off);
    __shared__ float part[4];
    if ((t & 63) == 0) part[t >> 6] = s;
    __syncthreads();
    if (t == 0) {
        float tot = part[0] + part[1] + part[2] + part[3];
        mean_out[row] = tot * (1.0f / (float)HW);
    }
}

// ---------------------------------------------------------------------------
// Kernel 2: the entire L=1 mamba block -> sigmoid gate. One block per batch.
// With L=1: scan h = dBx (h0=0), so A_log is dead, and
//   y[d] = (delta[d]*dot(B,C) + D_param[d]) * xs[d] * silu(z[d])
//   gate[c] = sigmoid( sum_d W_out[c,d] * y[d] )
// ---------------------------------------------------------------------------
__global__ __launch_bounds__(512) void mamba_gate_kernel(
    const float* __restrict__ mean_in,   // (8,512)
    const float* __restrict__ W_in,      // (2048,512)
    const float* __restrict__ conv_w,    // (1024,4)
    const float* __restrict__ conv_b,    // (1024,)
    const float* __restrict__ W_x,       // (64,1024)
    const float* __restrict__ W_dt,      // (1024,32)
    const float* __restrict__ b_dt,      // (1024,)
    const float* __restrict__ D_param,   // (1024,)
    const float* __restrict__ W_out,     // (512,1024)
    float* __restrict__ gate_out)        // (8,512)
{
    __shared__ float u[DMODEL];
    __shared__ float xs[DINNER];   // silu(conv(xp))
    __shared__ float sz[DINNER];   // silu(z)
    __shared__ float yv[DINNER];
    __shared__ float xdbl[64];     // dt(32) | B(16) | C(16)

    const int b = blockIdx.x;
    const int t = threadIdx.x;

    if (t < DMODEL) u[t] = mean_in[b * DMODEL + t];
    __syncthreads();

    // xz = W_in @ u : e in {t, t+512} -> xp part;  {t+1024, t+1536} -> z part
    const float4* uf = (const float4*)u;
    for (int half = 0; half < 2; ++half) {
        for (int k = 0; k < 2; ++k) {
            const int d = k * 512 + t;                 // 0..1023
            const int e = half * DINNER + d;
            const float4* wr = (const float4*)(W_in + (size_t)e * DMODEL);
            float acc = 0.f;
#pragma unroll 8
            for (int c4 = 0; c4 < DMODEL / 4; ++c4) {
                float4 w = wr[c4], uu = uf[c4];
                acc += w.x * uu.x + w.y * uu.y + w.z * uu.z + w.w * uu.w;
            }
            if (half == 0) {
                // causal depthwise conv at L=1: only last tap survives
                float xc = acc * conv_w[d * 4 + 3] + conv_b[d];
                xs[d] = xc / (1.f + expf(-xc));        // silu
            } else {
                sz[d] = acc / (1.f + expf(-acc));      // silu(z)
            }
        }
    }
    __syncthreads();

    // x_dbl = W_x @ xs  (64 outputs)
    if (t < 64) {
        const float* wr = W_x + (size_t)t * DINNER;
        float acc = 0.f;
        for (int d = 0; d < DINNER; ++d) acc += wr[d] * xs[d];
        xdbl[t] = acc;
    }
    __syncthreads();

    // bc = dot(B, C)  (computed redundantly per thread — LDS broadcast)
    float bc = 0.f;
#pragma unroll
    for (int n = 0; n < DSTATE; ++n)
        bc += xdbl[DTRANK + n] * xdbl[DTRANK + DSTATE + n];

    // delta = softplus(W_dt @ dt + b_dt);  y = (delta*bc + D)*xs*silu(z)
    for (int k = 0; k < 2; ++k) {
        const int d = k * 512 + t;
        float acc = b_dt[d];
        const float* wr = W_dt + (size_t)d * DTRANK;
#pragma unroll
        for (int r = 0; r < DTRANK; ++r) acc += wr[r] * xdbl[r];
        float delta = (acc > 20.f) ? acc : log1pf(expf(acc));
        yv[d] = (delta * bc + D_param[d]) * xs[d] * sz[d];
    }
    __syncthreads();

    // out = W_out @ y ; gate = sigmoid(out)
    {
        const float* wr = W_out + (size_t)t * DINNER;
        float acc = 0.f;
        for (int d = 0; d < DINNER; ++d) acc += wr[d] * yv[d];
        gate_out[b * DMODEL + t] = 1.f / (1.f + expf(-acc));
    }
}

// ---------------------------------------------------------------------------
// Kernel 3: out = x * gate[b,c]  (float4 grid-stride)
// ---------------------------------------------------------------------------
__global__ __launch_bounds__(256) void gate_mul_kernel(const float* __restrict__ x,
                                                       const float* __restrict__ gate,
                                                       float* __restrict__ out) {
    const float4* xi = (const float4*)x;
    float4* oo = (float4*)out;
    const size_t total4 = (size_t)BATCH * DMODEL * HW / 4;   // 16,777,216
    for (size_t q = (size_t)blockIdx.x * blockDim.x + threadIdx.x;
         q < total4; q += (size_t)gridDim.x * blockDim.x) {
        float g = gate[q >> 12];                 // 4096 float4 per (b,c) row
        float4 v = xi[q];
        v.x *= g; v.y *= g; v.z *= g; v.w *= g;
        oo[q] = v;
    }
}

extern "C" void kernel_launch(void* const* d_in, const int* in_sizes, int n_in,
                              void* d_out, int out_size, void* d_ws, size_t ws_size,
                              hipStream_t stream) {
    const float* x       = (const float*)d_in[0];
    const float* W_in    = (const float*)d_in[1];
    const float* conv_w  = (const float*)d_in[2];
    const float* conv_b  = (const float*)d_in[3];
    const float* W_x     = (const float*)d_in[4];
    const float* W_dt    = (const float*)d_in[5];
    const float* b_dt    = (const float*)d_in[6];
    // d_in[7] = A_log — mathematically dead at L=1 (h0 = 0)
    const float* D_param = (const float*)d_in[8];
    const float* W_out   = (const float*)d_in[9];
    float* out = (float*)d_out;

    float* mean_buf = (float*)d_ws;              // 4096 floats
    float* gate_buf = mean_buf + BATCH * DMODEL; // 4096 floats

    mean_kernel<<<BATCH * DMODEL, 256, 0, stream>>>(x, mean_buf);
    mamba_gate_kernel<<<BATCH, 512, 0, stream>>>(mean_buf, W_in, conv_w, conv_b,
                                                 W_x, W_dt, b_dt, D_param, W_out,
                                                 gate_buf);
    gate_mul_kernel<<<8192, 256, 0, stream>>>(x, gate_buf, out);
}

// Round 2
// 184.301 us; speedup vs baseline: 2.0772x; 2.0772x over previous
//
#include <hip/hip_runtime.h>
#include <math.h>

#define DMODEL 512
#define DINNER 1024
#define DTRANK 32
#define DSTATE 16
#define HW     16384   // 128*128
#define BATCH  8

__device__ __forceinline__ float wave_reduce(float s) {
#pragma unroll
    for (int off = 32; off; off >>= 1) s += __shfl_xor(s, off);
    return s;
}

// ---------------------------------------------------------------------------
// Kernel 1: mean over spatial dims. One block per (b,c) row of 16384 floats.
// ---------------------------------------------------------------------------
__global__ __launch_bounds__(256) void mean_kernel(const float* __restrict__ x,
                                                   float* __restrict__ mean_out) {
    const int row = blockIdx.x;                       // b*512 + c  (4096 rows)
    const float4* xr = (const float4*)(x + (size_t)row * HW);
    const int t = threadIdx.x;
    float s = 0.f;
#pragma unroll
    for (int j = 0; j < 16; ++j) {                    // 4096 float4 / 256 thr
        float4 v = xr[t + j * 256];
        s += v.x + v.y + v.z + v.w;
    }
    for (int off = 32; off; off >>= 1) s += __shfl_down(s, off);
    __shared__ float part[4];
    if ((t & 63) == 0) part[t >> 6] = s;
    __syncthreads();
    if (t == 0) {
        float tot = part[0] + part[1] + part[2] + part[3];
        mean_out[row] = tot * (1.0f / (float)HW);
    }
}

// ---------------------------------------------------------------------------
// K2a: xz = W_in @ u for all 8 batches, fused conv(tap-3)+silu epilogue.
// One wave per output row e (0..2047). 512 blocks x 256 threads.
//   e < 1024  -> xs_buf[b][e]   = silu(xz*conv_w[e,3] + conv_b[e])
//   e >= 1024 -> sz_buf[b][e-1024] = silu(xz)
// ---------------------------------------------------------------------------
__global__ __launch_bounds__(256) void k2a_win_kernel(
    const float* __restrict__ mean_in,   // (8,512)
    const float* __restrict__ W_in,      // (2048,512)
    const float* __restrict__ conv_w,    // (1024,4)
    const float* __restrict__ conv_b,    // (1024,)
    float* __restrict__ xs_buf,          // (8,1024)
    float* __restrict__ sz_buf)          // (8,1024)
{
    __shared__ float u[BATCH * DMODEL];               // 16 KB
    const int t = threadIdx.x;
#pragma unroll
    for (int i = 0; i < 16; ++i) u[t + i * 256] = mean_in[t + i * 256];
    __syncthreads();

    const int wave = blockIdx.x * 4 + (t >> 6);       // = e, 0..2047
    const int lane = t & 63;
    const float4* row = (const float4*)(W_in + (size_t)wave * DMODEL);
    const float4 w0 = row[lane];                      // floats 4*lane..
    const float4 w1 = row[lane + 64];                 // floats 4*(lane+64)..
    const float4* u4 = (const float4*)u;

    float acc[BATCH];
#pragma unroll
    for (int b = 0; b < BATCH; ++b) {
        float4 a = u4[b * 128 + lane];
        float4 c = u4[b * 128 + lane + 64];
        acc[b] = w0.x * a.x + w0.y * a.y + w0.z * a.z + w0.w * a.w
               + w1.x * c.x + w1.y * c.y + w1.z * c.z + w1.w * c.w;
    }
#pragma unroll
    for (int b = 0; b < BATCH; ++b) acc[b] = wave_reduce(acc[b]);

    if (lane == 0) {
        if (wave < DINNER) {
            const float cw = conv_w[wave * 4 + 3];
            const float cb = conv_b[wave];
#pragma unroll
            for (int b = 0; b < BATCH; ++b) {
                float xc = acc[b] * cw + cb;
                xs_buf[b * DINNER + wave] = xc / (1.f + expf(-xc));
            }
        } else {
            const int d = wave - DINNER;
#pragma unroll
            for (int b = 0; b < BATCH; ++b) {
                float zc = acc[b];
                sz_buf[b * DINNER + d] = zc / (1.f + expf(-zc));
            }
        }
    }
}

// ---------------------------------------------------------------------------
// K2b: per batch: x_dbl = W_x @ xs; bc = dot(B,C); delta = softplus(W_dt@dt+b);
//      y = (delta*bc + D)*xs*silu(z).  8 blocks x 256 threads (tiny).
// ---------------------------------------------------------------------------
__global__ __launch_bounds__(256) void k2b_mid_kernel(
    const float* __restrict__ xs_buf,    // (8,1024)
    const float* __restrict__ sz_buf,    // (8,1024)
    const float* __restrict__ W_x,       // (64,1024)
    const float* __restrict__ W_dt,      // (1024,32)
    const float* __restrict__ b_dt,      // (1024,)
    const float* __restrict__ D_param,   // (1024,)
    float* __restrict__ yv_buf)          // (8,1024)
{
    __shared__ float xs[DINNER];
    __shared__ float xdbl[64];
    const int b = blockIdx.x;
    const int t = threadIdx.x;
    const int lane = t & 63;
    const int wv = t >> 6;                            // 0..3

#pragma unroll
    for (int i = 0; i < 4; ++i) xs[t + i * 256] = xs_buf[b * DINNER + t + i * 256];
    __syncthreads();

    // x_dbl: 64 outputs, 4 waves x 16 outputs each; lanes split the 1024-dot
    const float4* xs4 = (const float4*)xs;
    for (int oi = 0; oi < 16; ++oi) {
        const int o = wv * 16 + oi;
        const float4* wr = (const float4*)(W_x + (size_t)o * DINNER);
        float acc = 0.f;
#pragma unroll
        for (int j = 0; j < 4; ++j) {
            float4 w = wr[lane + j * 64];
            float4 v = xs4[lane + j * 64];
            acc += w.x * v.x + w.y * v.y + w.z * v.z + w.w * v.w;
        }
        acc = wave_reduce(acc);
        if (lane == 0) xdbl[o] = acc;
    }
    __syncthreads();

    float bc = 0.f;
#pragma unroll
    for (int n = 0; n < DSTATE; ++n)
        bc += xdbl[DTRANK + n] * xdbl[DTRANK + DSTATE + n];

#pragma unroll
    for (int k = 0; k < 4; ++k) {
        const int d = t + k * 256;
        float acc = b_dt[d];
        const float4* wr = (const float4*)(W_dt + (size_t)d * DTRANK);
        const float4* dt4 = (const float4*)xdbl;
#pragma unroll
        for (int r = 0; r < 8; ++r) {
            float4 w = wr[r]; float4 v = dt4[r];
            acc += w.x * v.x + w.y * v.y + w.z * v.z + w.w * v.w;
        }
        float delta = (acc > 20.f) ? acc : log1pf(expf(acc));
        yv_buf[b * DINNER + d] =
            (delta * bc + D_param[d]) * xs[d] * sz_buf[b * DINNER + d];
    }
}

// ---------------------------------------------------------------------------
// K2c: gate = sigmoid(W_out @ y). One wave per channel c (0..511), all 8
// batches per wave. 128 blocks x 256 threads.
// ---------------------------------------------------------------------------
__global__ __launch_bounds__(256) void k2c_wout_kernel(
    const float* __restrict__ yv_buf,    // (8,1024)
    const float* __restrict__ W_out,     // (512,1024)
    float* __restrict__ gate_out)        // (8,512)
{
    __shared__ float yv[BATCH * DINNER];              // 32 KB
    const int t = threadIdx.x;
#pragma unroll
    for (int i = 0; i < 32; ++i) yv[t + i * 256] = yv_buf[t + i * 256];
    __syncthreads();

    const int wave = blockIdx.x * 4 + (t >> 6);       // = c, 0..511
    const int lane = t & 63;
    const float4* row = (const float4*)(W_out + (size_t)wave * DINNER);
    const float4* yv4 = (const float4*)yv;

    float acc[BATCH];
#pragma unroll
    for (int b = 0; b < BATCH; ++b) acc[b] = 0.f;
#pragma unroll
    for (int j = 0; j < 4; ++j) {
        float4 w = row[lane + j * 64];
#pragma unroll
        for (int b = 0; b < BATCH; ++b) {
            float4 v = yv4[b * 256 + lane + j * 64];
            acc[b] += w.x * v.x + w.y * v.y + w.z * v.z + w.w * v.w;
        }
    }
#pragma unroll
    for (int b = 0; b < BATCH; ++b) acc[b] = wave_reduce(acc[b]);

    if (lane == 0) {
#pragma unroll
        for (int b = 0; b < BATCH; ++b)
            gate_out[b * DMODEL + wave] = 1.f / (1.f + expf(-acc[b]));
    }
}

// ---------------------------------------------------------------------------
// Kernel 3: out = x * gate[b,c]  (float4 grid-stride)
// ---------------------------------------------------------------------------
__global__ __launch_bounds__(256) void gate_mul_kernel(const float* __restrict__ x,
                                                       const float* __restrict__ gate,
                                                       float* __restrict__ out) {
    const float4* xi = (const float4*)x;
    float4* oo = (float4*)out;
    const size_t total4 = (size_t)BATCH * DMODEL * HW / 4;   // 16,777,216
    for (size_t q = (size_t)blockIdx.x * blockDim.x + threadIdx.x;
         q < total4; q += (size_t)gridDim.x * blockDim.x) {
        float g = gate[q >> 12];                 // 4096 float4 per (b,c) row
        float4 v = xi[q];
        v.x *= g; v.y *= g; v.z *= g; v.w *= g;
        oo[q] = v;
    }
}

extern "C" void kernel_launch(void* const* d_in, const int* in_sizes, int n_in,
                              void* d_out, int out_size, void* d_ws, size_t ws_size,
                              hipStream_t stream) {
    const float* x       = (const float*)d_in[0];
    const float* W_in    = (const float*)d_in[1];
    const float* conv_w  = (const float*)d_in[2];
    const float* conv_b  = (const float*)d_in[3];
    const float* W_x     = (const float*)d_in[4];
    const float* W_dt    = (const float*)d_in[5];
    const float* b_dt    = (const float*)d_in[6];
    // d_in[7] = A_log — mathematically dead at L=1 (h0 = 0)
    const float* D_param = (const float*)d_in[8];
    const float* W_out   = (const float*)d_in[9];
    float* out = (float*)d_out;

    float* mean_buf = (float*)d_ws;                  // 4096
    float* gate_buf = mean_buf + BATCH * DMODEL;     // 4096
    float* xs_buf   = gate_buf + BATCH * DMODEL;     // 8192
    float* sz_buf   = xs_buf + BATCH * DINNER;       // 8192
    float* yv_buf   = sz_buf + BATCH * DINNER;       // 8192

    mean_kernel<<<BATCH * DMODEL, 256, 0, stream>>>(x, mean_buf);
    k2a_win_kernel<<<512, 256, 0, stream>>>(mean_buf, W_in, conv_w, conv_b,
                                            xs_buf, sz_buf);
    k2b_mid_kernel<<<BATCH, 256, 0, stream>>>(xs_buf, sz_buf, W_x, W_dt, b_dt,
                                              D_param, yv_buf);
    k2c_wout_kernel<<<128, 256, 0, stream>>>(yv_buf, W_out, gate_buf);
    gate_mul_kernel<<<8192, 256, 0, stream>>>(x, gate_buf, out);
}

// Round 3
// 152.872 us; speedup vs baseline: 2.5042x; 1.2056x over previous
//
#include <hip/hip_runtime.h>
#include <math.h>

#define DMODEL 512
#define DINNER 1024
#define DTRANK 32
#define DSTATE 16
#define HW     16384   // 128*128
#define BATCH  8

typedef float vf4 __attribute__((ext_vector_type(4)));

__device__ __forceinline__ float wave_reduce(float s) {
#pragma unroll
    for (int off = 32; off; off >>= 1) s += __shfl_xor(s, off);
    return s;
}

// ---------------------------------------------------------------------------
// Kernel 1: mean over spatial dims. One block per (b,c) row of 16384 floats.
// Regular loads on purpose: pulls x into Infinity Cache for the multiply pass.
// ---------------------------------------------------------------------------
__global__ __launch_bounds__(256) void mean_kernel(const float* __restrict__ x,
                                                   float* __restrict__ mean_out) {
    const int row = blockIdx.x;                       // b*512 + c  (4096 rows)
    const vf4* xr = (const vf4*)(x + (size_t)row * HW);
    const int t = threadIdx.x;
    float s = 0.f;
#pragma unroll
    for (int j = 0; j < 16; ++j) {                    // 4096 float4 / 256 thr
        vf4 v = xr[t + j * 256];
        s += v.x + v.y + v.z + v.w;
    }
    for (int off = 32; off; off >>= 1) s += __shfl_down(s, off);
    __shared__ float part[4];
    if ((t & 63) == 0) part[t >> 6] = s;
    __syncthreads();
    if (t == 0) {
        float tot = part[0] + part[1] + part[2] + part[3];
        mean_out[row] = tot * (1.0f / (float)HW);
    }
}

// ---------------------------------------------------------------------------
// K2a: xz = W_in @ u for all 8 batches, fused conv(tap-3)+silu epilogue.
// One wave per output row e (0..2047). 512 blocks x 256 threads.
// ---------------------------------------------------------------------------
__global__ __launch_bounds__(256) void k2a_win_kernel(
    const float* __restrict__ mean_in,   // (8,512)
    const float* __restrict__ W_in,      // (2048,512)
    const float* __restrict__ conv_w,    // (1024,4)
    const float* __restrict__ conv_b,    // (1024,)
    float* __restrict__ xs_buf,          // (8,1024)
    float* __restrict__ sz_buf)          // (8,1024)
{
    __shared__ float u[BATCH * DMODEL];               // 16 KB
    const int t = threadIdx.x;
#pragma unroll
    for (int i = 0; i < 16; ++i) u[t + i * 256] = mean_in[t + i * 256];
    __syncthreads();

    const int wave = blockIdx.x * 4 + (t >> 6);       // = e, 0..2047
    const int lane = t & 63;
    const vf4* row = (const vf4*)(W_in + (size_t)wave * DMODEL);
    const vf4 w0 = row[lane];
    const vf4 w1 = row[lane + 64];
    const vf4* u4 = (const vf4*)u;

    float acc[BATCH];
#pragma unroll
    for (int b = 0; b < BATCH; ++b) {
        vf4 a = u4[b * 128 + lane];
        vf4 c = u4[b * 128 + lane + 64];
        acc[b] = w0.x * a.x + w0.y * a.y + w0.z * a.z + w0.w * a.w
               + w1.x * c.x + w1.y * c.y + w1.z * c.z + w1.w * c.w;
    }
#pragma unroll
    for (int b = 0; b < BATCH; ++b) acc[b] = wave_reduce(acc[b]);

    if (lane == 0) {
        if (wave < DINNER) {
            const float cw = conv_w[wave * 4 + 3];
            const float cb = conv_b[wave];
#pragma unroll
            for (int b = 0; b < BATCH; ++b) {
                float xc = acc[b] * cw + cb;
                xs_buf[b * DINNER + wave] = xc / (1.f + expf(-xc));
            }
        } else {
            const int d = wave - DINNER;
#pragma unroll
            for (int b = 0; b < BATCH; ++b) {
                float zc = acc[b];
                sz_buf[b * DINNER + d] = zc / (1.f + expf(-zc));
            }
        }
    }
}

// ---------------------------------------------------------------------------
// K2b: per batch: x_dbl = W_x @ xs; bc = dot(B,C); delta = softplus(W_dt@dt+b);
//      y = (delta*bc + D)*xs*silu(z).  8 blocks x 256 threads (tiny).
// ---------------------------------------------------------------------------
__global__ __launch_bounds__(256) void k2b_mid_kernel(
    const float* __restrict__ xs_buf,    // (8,1024)
    const float* __restrict__ sz_buf,    // (8,1024)
    const float* __restrict__ W_x,       // (64,1024)
    const float* __restrict__ W_dt,      // (1024,32)
    const float* __restrict__ b_dt,      // (1024,)
    const float* __restrict__ D_param,   // (1024,)
    float* __restrict__ yv_buf)          // (8,1024)
{
    __shared__ float xs[DINNER];
    __shared__ float xdbl[64];
    const int b = blockIdx.x;
    const int t = threadIdx.x;
    const int lane = t & 63;
    const int wv = t >> 6;                            // 0..3

#pragma unroll
    for (int i = 0; i < 4; ++i) xs[t + i * 256] = xs_buf[b * DINNER + t + i * 256];
    __syncthreads();

    const vf4* xs4 = (const vf4*)xs;
    for (int oi = 0; oi < 16; ++oi) {
        const int o = wv * 16 + oi;
        const vf4* wr = (const vf4*)(W_x + (size_t)o * DINNER);
        float acc = 0.f;
#pragma unroll
        for (int j = 0; j < 4; ++j) {
            vf4 w = wr[lane + j * 64];
            vf4 v = xs4[lane + j * 64];
            acc += w.x * v.x + w.y * v.y + w.z * v.z + w.w * v.w;
        }
        acc = wave_reduce(acc);
        if (lane == 0) xdbl[o] = acc;
    }
    __syncthreads();

    float bc = 0.f;
#pragma unroll
    for (int n = 0; n < DSTATE; ++n)
        bc += xdbl[DTRANK + n] * xdbl[DTRANK + DSTATE + n];

#pragma unroll
    for (int k = 0; k < 4; ++k) {
        const int d = t + k * 256;
        float acc = b_dt[d];
        const vf4* wr = (const vf4*)(W_dt + (size_t)d * DTRANK);
        const vf4* dt4 = (const vf4*)xdbl;
#pragma unroll
        for (int r = 0; r < 8; ++r) {
            vf4 w = wr[r]; vf4 v = dt4[r];
            acc += w.x * v.x + w.y * v.y + w.z * v.z + w.w * v.w;
        }
        float delta = (acc > 20.f) ? acc : log1pf(expf(acc));
        yv_buf[b * DINNER + d] =
            (delta * bc + D_param[d]) * xs[d] * sz_buf[b * DINNER + d];
    }
}

// ---------------------------------------------------------------------------
// K2c: gate = sigmoid(W_out @ y). One wave per channel c (0..511), all 8
// batches per wave. 128 blocks x 256 threads.
// ---------------------------------------------------------------------------
__global__ __launch_bounds__(256) void k2c_wout_kernel(
    const float* __restrict__ yv_buf,    // (8,1024)
    const float* __restrict__ W_out,     // (512,1024)
    float* __restrict__ gate_out)        // (8,512)
{
    __shared__ float yv[BATCH * DINNER];              // 32 KB
    const int t = threadIdx.x;
#pragma unroll
    for (int i = 0; i < 32; ++i) yv[t + i * 256] = yv_buf[t + i * 256];
    __syncthreads();

    const int wave = blockIdx.x * 4 + (t >> 6);       // = c, 0..511
    const int lane = t & 63;
    const vf4* row = (const vf4*)(W_out + (size_t)wave * DINNER);
    const vf4* yv4 = (const vf4*)yv;

    float acc[BATCH];
#pragma unroll
    for (int b = 0; b < BATCH; ++b) acc[b] = 0.f;
#pragma unroll
    for (int j = 0; j < 4; ++j) {
        vf4 w = row[lane + j * 64];
#pragma unroll
        for (int b = 0; b < BATCH; ++b) {
            vf4 v = yv4[b * 256 + lane + j * 64];
            acc[b] += w.x * v.x + w.y * v.y + w.z * v.z + w.w * v.w;
        }
    }
#pragma unroll
    for (int b = 0; b < BATCH; ++b) acc[b] = wave_reduce(acc[b]);

    if (lane == 0) {
#pragma unroll
        for (int b = 0; b < BATCH; ++b)
            gate_out[b * DMODEL + wave] = 1.f / (1.f + expf(-acc[b]));
    }
}

// ---------------------------------------------------------------------------
// Kernel 3: out = x * gate[b,c]. One block per (b,c) row: gate is one uniform
// scalar load; x read hits L3 (populated by mean pass); out written with
// NONTEMPORAL stores so it doesn't evict x from Infinity Cache.
// ---------------------------------------------------------------------------
__global__ __launch_bounds__(256) void gate_mul_kernel(const float* __restrict__ x,
                                                       const float* __restrict__ gate,
                                                       float* __restrict__ out) {
    const int row = blockIdx.x;                       // b*512 + c
    const float g = gate[row];                        // uniform -> s_load
    const vf4* xi = (const vf4*)(x + (size_t)row * HW);
    vf4* oo = (vf4*)(out + (size_t)row * HW);
    const int t = threadIdx.x;
#pragma unroll
    for (int j = 0; j < 16; ++j) {
        vf4 v = xi[t + j * 256];
        v *= g;
        __builtin_nontemporal_store(v, &oo[t + j * 256]);
    }
}

extern "C" void kernel_launch(void* const* d_in, const int* in_sizes, int n_in,
                              void* d_out, int out_size, void* d_ws, size_t ws_size,
                              hipStream_t stream) {
    const float* x       = (const float*)d_in[0];
    const float* W_in    = (const float*)d_in[1];
    const float* conv_w  = (const float*)d_in[2];
    const float* conv_b  = (const float*)d_in[3];
    const float* W_x     = (const float*)d_in[4];
    const float* W_dt    = (const float*)d_in[5];
    const float* b_dt    = (const float*)d_in[6];
    // d_in[7] = A_log — mathematically dead at L=1 (h0 = 0)
    const float* D_param = (const float*)d_in[8];
    const float* W_out   = (const float*)d_in[9];
    float* out = (float*)d_out;

    float* mean_buf = (float*)d_ws;                  // 4096
    float* gate_buf = mean_buf + BATCH * DMODEL;     // 4096
    float* xs_buf   = gate_buf + BATCH * DMODEL;     // 8192
    float* sz_buf   = xs_buf + BATCH * DINNER;       // 8192
    float* yv_buf   = sz_buf + BATCH * DINNER;       // 8192

    mean_kernel<<<BATCH * DMODEL, 256, 0, stream>>>(x, mean_buf);
    k2a_win_kernel<<<512, 256, 0, stream>>>(mean_buf, W_in, conv_w, conv_b,
                                            xs_buf, sz_buf);
    k2b_mid_kernel<<<BATCH, 256, 0, stream>>>(xs_buf, sz_buf, W_x, W_dt, b_dt,
                                              D_param, yv_buf);
    k2c_wout_kernel<<<128, 256, 0, stream>>>(yv_buf, W_out, gate_buf);
    gate_mul_kernel<<<BATCH * DMODEL, 256, 0, stream>>>(x, gate_buf, out);
}

// Round 4
// 149.045 us; speedup vs baseline: 2.5685x; 1.0257x over previous
//
#include <hip/hip_runtime.h>
#include <math.h>

#define DMODEL 512
#define DINNER 1024
#define DTRANK 32
#define DSTATE 16
#define HW     16384   // 128*128
#define BATCH  8

typedef float vf4 __attribute__((ext_vector_type(4)));

__device__ __forceinline__ float wave_reduce(float s) {
#pragma unroll
    for (int off = 32; off; off >>= 1) s += __shfl_xor(s, off);
    return s;
}

// ---------------------------------------------------------------------------
// Kernel 1: mean over spatial dims. One block per (b,c) row of 16384 floats.
// Regular loads on purpose: leaves x resident in Infinity Cache.
// ---------------------------------------------------------------------------
__global__ __launch_bounds__(256) void mean_kernel(const float* __restrict__ x,
                                                   float* __restrict__ mean_out) {
    const int row = blockIdx.x;                       // b*512 + c  (4096 rows)
    const vf4* xr = (const vf4*)(x + (size_t)row * HW);
    const int t = threadIdx.x;
    float s = 0.f;
#pragma unroll
    for (int j = 0; j < 16; ++j) {                    // 4096 float4 / 256 thr
        vf4 v = xr[t + j * 256];
        s += v.x + v.y + v.z + v.w;
    }
    for (int off = 32; off; off >>= 1) s += __shfl_down(s, off);
    __shared__ float part[4];
    if ((t & 63) == 0) part[t >> 6] = s;
    __syncthreads();
    if (t == 0) {
        float tot = part[0] + part[1] + part[2] + part[3];
        mean_out[row] = tot * (1.0f / (float)HW);
    }
}

// ---------------------------------------------------------------------------
// K2a: xz = W_in @ u for all 8 batches, fused conv(tap-3)+silu epilogue.
// One wave per output row e (0..2047). 512 blocks x 256 threads.
// ---------------------------------------------------------------------------
__global__ __launch_bounds__(256) void k2a_win_kernel(
    const float* __restrict__ mean_in,   // (8,512)
    const float* __restrict__ W_in,      // (2048,512)
    const float* __restrict__ conv_w,    // (1024,4)
    const float* __restrict__ conv_b,    // (1024,)
    float* __restrict__ xs_buf,          // (8,1024)
    float* __restrict__ sz_buf)          // (8,1024)
{
    __shared__ float u[BATCH * DMODEL];               // 16 KB
    const int t = threadIdx.x;
#pragma unroll
    for (int i = 0; i < 16; ++i) u[t + i * 256] = mean_in[t + i * 256];
    __syncthreads();

    const int wave = blockIdx.x * 4 + (t >> 6);       // = e, 0..2047
    const int lane = t & 63;
    const vf4* row = (const vf4*)(W_in + (size_t)wave * DMODEL);
    const vf4 w0 = row[lane];
    const vf4 w1 = row[lane + 64];
    const vf4* u4 = (const vf4*)u;

    float acc[BATCH];
#pragma unroll
    for (int b = 0; b < BATCH; ++b) {
        vf4 a = u4[b * 128 + lane];
        vf4 c = u4[b * 128 + lane + 64];
        acc[b] = w0.x * a.x + w0.y * a.y + w0.z * a.z + w0.w * a.w
               + w1.x * c.x + w1.y * c.y + w1.z * c.z + w1.w * c.w;
    }
#pragma unroll
    for (int b = 0; b < BATCH; ++b) acc[b] = wave_reduce(acc[b]);

    if (lane == 0) {
        if (wave < DINNER) {
            const float cw = conv_w[wave * 4 + 3];
            const float cb = conv_b[wave];
#pragma unroll
            for (int b = 0; b < BATCH; ++b) {
                float xc = acc[b] * cw + cb;
                xs_buf[b * DINNER + wave] = xc / (1.f + expf(-xc));
            }
        } else {
            const int d = wave - DINNER;
#pragma unroll
            for (int b = 0; b < BATCH; ++b) {
                float zc = acc[b];
                sz_buf[b * DINNER + d] = zc / (1.f + expf(-zc));
            }
        }
    }
}

// ---------------------------------------------------------------------------
// K2b: per batch: x_dbl = W_x @ xs; bc = dot(B,C); delta = softplus(W_dt@dt+b);
//      y = (delta*bc + D)*xs*silu(z).  8 blocks x 256 threads (tiny).
// ---------------------------------------------------------------------------
__global__ __launch_bounds__(256) void k2b_mid_kernel(
    const float* __restrict__ xs_buf,    // (8,1024)
    const float* __restrict__ sz_buf,    // (8,1024)
    const float* __restrict__ W_x,       // (64,1024)
    const float* __restrict__ W_dt,      // (1024,32)
    const float* __restrict__ b_dt,      // (1024,)
    const float* __restrict__ D_param,   // (1024,)
    float* __restrict__ yv_buf)          // (8,1024)
{
    __shared__ float xs[DINNER];
    __shared__ float xdbl[64];
    const int b = blockIdx.x;
    const int t = threadIdx.x;
    const int lane = t & 63;
    const int wv = t >> 6;                            // 0..3

#pragma unroll
    for (int i = 0; i < 4; ++i) xs[t + i * 256] = xs_buf[b * DINNER + t + i * 256];
    __syncthreads();

    const vf4* xs4 = (const vf4*)xs;
    for (int oi = 0; oi < 16; ++oi) {
        const int o = wv * 16 + oi;
        const vf4* wr = (const vf4*)(W_x + (size_t)o * DINNER);
        float acc = 0.f;
#pragma unroll
        for (int j = 0; j < 4; ++j) {
            vf4 w = wr[lane + j * 64];
            vf4 v = xs4[lane + j * 64];
            acc += w.x * v.x + w.y * v.y + w.z * v.z + w.w * v.w;
        }
        acc = wave_reduce(acc);
        if (lane == 0) xdbl[o] = acc;
    }
    __syncthreads();

    float bc = 0.f;
#pragma unroll
    for (int n = 0; n < DSTATE; ++n)
        bc += xdbl[DTRANK + n] * xdbl[DTRANK + DSTATE + n];

#pragma unroll
    for (int k = 0; k < 4; ++k) {
        const int d = t + k * 256;
        float acc = b_dt[d];
        const vf4* wr = (const vf4*)(W_dt + (size_t)d * DTRANK);
        const vf4* dt4 = (const vf4*)xdbl;
#pragma unroll
        for (int r = 0; r < 8; ++r) {
            vf4 w = wr[r]; vf4 v = dt4[r];
            acc += w.x * v.x + w.y * v.y + w.z * v.z + w.w * v.w;
        }
        float delta = (acc > 20.f) ? acc : log1pf(expf(acc));
        yv_buf[b * DINNER + d] =
            (delta * bc + D_param[d]) * xs[d] * sz_buf[b * DINNER + d];
    }
}

// ---------------------------------------------------------------------------
// Kernel 3 (fused with old k2c): per (b,c) row, compute
//   gate = sigmoid(W_out[c,:] . yv[b,:])   (redundant per-wave 1024-dot; its
//   8 KiB of loads issue before the 64 KiB x prefetch and finish under it)
// then out = x * gate with NONTEMPORAL stores. Rows traversed in REVERSE so
// out's write-allocations (if L3 ignores nt) evict the already-consumed end
// of x rather than the lines needed next.
// ---------------------------------------------------------------------------
__global__ __launch_bounds__(256) void gate_mul_kernel(
    const float* __restrict__ x,
    const float* __restrict__ yv_buf,    // (8,1024)
    const float* __restrict__ W_out,     // (512,1024)
    float* __restrict__ out)
{
    const int row = (BATCH * DMODEL - 1) - blockIdx.x;   // reverse traversal
    const int b = row >> 9;
    const int c = row & 511;
    const int t = threadIdx.x;
    const int lane = t & 63;

    // --- gate dot loads first (small, L2/L3-hot after first blocks) ---
    const vf4* wr = (const vf4*)(W_out + (size_t)c * DINNER);
    const vf4* yv = (const vf4*)(yv_buf + (size_t)b * DINNER);
    vf4 w[4], y[4];
#pragma unroll
    for (int j = 0; j < 4; ++j) { w[j] = wr[lane + j * 64]; y[j] = yv[lane + j * 64]; }

    // --- x prefetch (issued before the dot's waitcnt drains) ---
    const vf4* xi = (const vf4*)(x + (size_t)row * HW);
    vf4* oo = (vf4*)(out + (size_t)row * HW);
    vf4 v[16];
#pragma unroll
    for (int j = 0; j < 16; ++j) v[j] = xi[t + j * 256];

    float acc = 0.f;
#pragma unroll
    for (int j = 0; j < 4; ++j)
        acc += w[j].x * y[j].x + w[j].y * y[j].y + w[j].z * y[j].z + w[j].w * y[j].w;
    acc = wave_reduce(acc);                              // all lanes get sum
    const float g = 1.f / (1.f + expf(-acc));

#pragma unroll
    for (int j = 0; j < 16; ++j) {
        vf4 o = v[j] * g;
        __builtin_nontemporal_store(o, &oo[t + j * 256]);
    }
}

extern "C" void kernel_launch(void* const* d_in, const int* in_sizes, int n_in,
                              void* d_out, int out_size, void* d_ws, size_t ws_size,
                              hipStream_t stream) {
    const float* x       = (const float*)d_in[0];
    const float* W_in    = (const float*)d_in[1];
    const float* conv_w  = (const float*)d_in[2];
    const float* conv_b  = (const float*)d_in[3];
    const float* W_x     = (const float*)d_in[4];
    const float* W_dt    = (const float*)d_in[5];
    const float* b_dt    = (const float*)d_in[6];
    // d_in[7] = A_log — mathematically dead at L=1 (h0 = 0)
    const float* D_param = (const float*)d_in[8];
    const float* W_out   = (const float*)d_in[9];
    float* out = (float*)d_out;

    float* mean_buf = (float*)d_ws;                  // 4096
    float* xs_buf   = mean_buf + BATCH * DMODEL;     // 8192
    float* sz_buf   = xs_buf + BATCH * DINNER;       // 8192
    float* yv_buf   = sz_buf + BATCH * DINNER;       // 8192

    mean_kernel<<<BATCH * DMODEL, 256, 0, stream>>>(x, mean_buf);
    k2a_win_kernel<<<512, 256, 0, stream>>>(mean_buf, W_in, conv_w, conv_b,
                                            xs_buf, sz_buf);
    k2b_mid_kernel<<<BATCH, 256, 0, stream>>>(xs_buf, sz_buf, W_x, W_dt, b_dt,
                                              D_param, yv_buf);
    gate_mul_kernel<<<BATCH * DMODEL, 256, 0, stream>>>(x, yv_buf, W_out, out);
}

// Round 5
// 144.777 us; speedup vs baseline: 2.6443x; 1.0295x over previous
//
#include <hip/hip_runtime.h>
#include <math.h>

#define DMODEL 512
#define DINNER 1024
#define DTRANK 32
#define DSTATE 16
#define HW     16384   // 128*128
#define BATCH  8

typedef float vf4 __attribute__((ext_vector_type(4)));

__device__ __forceinline__ float wave_reduce(float s) {
#pragma unroll
    for (int off = 32; off; off >>= 1) s += __shfl_xor(s, off);
    return s;
}

__device__ __forceinline__ float dot4(vf4 a, vf4 b) {
    return a.x * b.x + a.y * b.y + a.z * b.z + a.w * b.w;
}

// ---------------------------------------------------------------------------
// Kernel 1: mean over spatial dims. One block per (b,c) row of 16384 floats.
// Forward traversal on purpose (ping-pong with gate_mul's reverse pass).
// ---------------------------------------------------------------------------
__global__ __launch_bounds__(256) void mean_kernel(const float* __restrict__ x,
                                                   float* __restrict__ mean_out) {
    const int row = blockIdx.x;                       // b*512 + c  (4096 rows)
    const vf4* xr = (const vf4*)(x + (size_t)row * HW);
    const int t = threadIdx.x;
    float s = 0.f;
#pragma unroll
    for (int j = 0; j < 16; ++j) {                    // 4096 float4 / 256 thr
        vf4 v = xr[t + j * 256];
        s += v.x + v.y + v.z + v.w;
    }
    for (int off = 32; off; off >>= 1) s += __shfl_down(s, off);
    __shared__ float part[4];
    if ((t & 63) == 0) part[t >> 6] = s;
    __syncthreads();
    if (t == 0) {
        float tot = part[0] + part[1] + part[2] + part[3];
        mean_out[row] = tot * (1.0f / (float)HW);
    }
}

// ---------------------------------------------------------------------------
// K2a: xz = W_in @ u, fused conv(tap-3)+silu epilogue. One block per W_in row
// (2048 blocks); the 4 waves each own 2 batches; W_in row shared via L1.
// ---------------------------------------------------------------------------
__global__ __launch_bounds__(256) void k2a_win_kernel(
    const float* __restrict__ mean_in,   // (8,512)
    const float* __restrict__ W_in,      // (2048,512)
    const float* __restrict__ conv_w,    // (1024,4)
    const float* __restrict__ conv_b,    // (1024,)
    float* __restrict__ xs_buf,          // (8,1024)
    float* __restrict__ sz_buf)          // (8,1024)
{
    const int e = blockIdx.x;                         // 0..2047
    const int t = threadIdx.x;
    const int lane = t & 63;
    const int wv = t >> 6;                            // 0..3 -> batches 2wv,2wv+1

    const vf4* row = (const vf4*)(W_in + (size_t)e * DMODEL);
    const vf4 w0 = row[lane];
    const vf4 w1 = row[lane + 64];
    const vf4* u4 = (const vf4*)mean_in;

    float acc[2];
#pragma unroll
    for (int k = 0; k < 2; ++k) {
        const int b = wv * 2 + k;
        vf4 a = u4[b * 128 + lane];
        vf4 c = u4[b * 128 + lane + 64];
        acc[k] = dot4(w0, a) + dot4(w1, c);
        acc[k] = wave_reduce(acc[k]);
    }

    if (lane == 0) {
        if (e < DINNER) {
            const float cw = conv_w[e * 4 + 3];
            const float cb = conv_b[e];
#pragma unroll
            for (int k = 0; k < 2; ++k) {
                float xc = acc[k] * cw + cb;
                xs_buf[(wv * 2 + k) * DINNER + e] = xc / (1.f + expf(-xc));
            }
        } else {
            const int d = e - DINNER;
#pragma unroll
            for (int k = 0; k < 2; ++k) {
                float zc = acc[k];
                sz_buf[(wv * 2 + k) * DINNER + d] = zc / (1.f + expf(-zc));
            }
        }
    }
}

// ---------------------------------------------------------------------------
// K2b: per batch: x_dbl = W_x @ xs; bc = dot(B,C); delta = softplus(W_dt@dt+b);
//      y = (delta*bc + D)*xs*silu(z).  8 blocks x 512 threads.
// ---------------------------------------------------------------------------
__global__ __launch_bounds__(512) void k2b_mid_kernel(
    const float* __restrict__ xs_buf,    // (8,1024)
    const float* __restrict__ sz_buf,    // (8,1024)
    const float* __restrict__ W_x,       // (64,1024)
    const float* __restrict__ W_dt,      // (1024,32)
    const float* __restrict__ b_dt,      // (1024,)
    const float* __restrict__ D_param,   // (1024,)
    float* __restrict__ yv_buf)          // (8,1024)
{
    __shared__ float xs[DINNER];
    __shared__ float xdbl[64];
    const int b = blockIdx.x;
    const int t = threadIdx.x;
    const int lane = t & 63;
    const int wv = t >> 6;                            // 0..7

#pragma unroll
    for (int i = 0; i < 2; ++i) xs[t + i * 512] = xs_buf[b * DINNER + t + i * 512];
    __syncthreads();

    // x_dbl: 64 outputs, 8 waves x 8 outputs each; lanes split the 1024-dot
    const vf4* xs4 = (const vf4*)xs;
    for (int oi = 0; oi < 8; ++oi) {
        const int o = wv * 8 + oi;
        const vf4* wr = (const vf4*)(W_x + (size_t)o * DINNER);
        float acc = 0.f;
#pragma unroll
        for (int j = 0; j < 4; ++j)
            acc += dot4(wr[lane + j * 64], xs4[lane + j * 64]);
        acc = wave_reduce(acc);
        if (lane == 0) xdbl[o] = acc;
    }
    __syncthreads();

    float bc = 0.f;
#pragma unroll
    for (int n = 0; n < DSTATE; ++n)
        bc += xdbl[DTRANK + n] * xdbl[DTRANK + DSTATE + n];

#pragma unroll
    for (int k = 0; k < 2; ++k) {
        const int d = t + k * 512;
        float acc = b_dt[d];
        const vf4* wr = (const vf4*)(W_dt + (size_t)d * DTRANK);
        const vf4* dt4 = (const vf4*)xdbl;
#pragma unroll
        for (int r = 0; r < 8; ++r)
            acc += dot4(wr[r], dt4[r]);
        float delta = (acc > 20.f) ? acc : log1pf(expf(acc));
        yv_buf[b * DINNER + d] =
            (delta * bc + D_param[d]) * xs[d] * sz_buf[b * DINNER + d];
    }
}

// ---------------------------------------------------------------------------
// Kernel 3: per (b,c) row: gate = sigmoid(W_out[c,:] . yv[b,:]) computed
// redundantly per wave, then a low-VGPR load-mul-store stream of the row with
// NONTEMPORAL stores. Reverse traversal ping-pongs L3 residency with the mean
// pass's forward read.
// ---------------------------------------------------------------------------
__global__ __launch_bounds__(256, 6) void gate_mul_kernel(
    const float* __restrict__ x,
    const float* __restrict__ yv_buf,    // (8,1024)
    const float* __restrict__ W_out,     // (512,1024)
    float* __restrict__ out)
{
    const int row = (BATCH * DMODEL - 1) - blockIdx.x;   // reverse traversal
    const int b = row >> 9;
    const int c = row & 511;
    const int t = threadIdx.x;
    const int lane = t & 63;

    const vf4* wr = (const vf4*)(W_out + (size_t)c * DINNER);
    const vf4* yv = (const vf4*)(yv_buf + (size_t)b * DINNER);
    float acc = 0.f;
#pragma unroll
    for (int j = 0; j < 4; ++j)
        acc += dot4(wr[lane + j * 64], yv[lane + j * 64]);
    acc = wave_reduce(acc);
    const float g = 1.f / (1.f + expf(-acc));

    const vf4* xi = (const vf4*)(x + (size_t)row * HW);
    vf4* oo = (vf4*)(out + (size_t)row * HW);
#pragma unroll 4
    for (int j = 0; j < 16; ++j) {
        vf4 v = xi[t + j * 256] * g;
        __builtin_nontemporal_store(v, &oo[t + j * 256]);
    }
}

extern "C" void kernel_launch(void* const* d_in, const int* in_sizes, int n_in,
                              void* d_out, int out_size, void* d_ws, size_t ws_size,
                              hipStream_t stream) {
    const float* x       = (const float*)d_in[0];
    const float* W_in    = (const float*)d_in[1];
    const float* conv_w  = (const float*)d_in[2];
    const float* conv_b  = (const float*)d_in[3];
    const float* W_x     = (const float*)d_in[4];
    const float* W_dt    = (const float*)d_in[5];
    const float* b_dt    = (const float*)d_in[6];
    // d_in[7] = A_log — mathematically dead at L=1 (h0 = 0)
    const float* D_param = (const float*)d_in[8];
    const float* W_out   = (const float*)d_in[9];
    float* out = (float*)d_out;

    float* mean_buf = (float*)d_ws;                  // 4096
    float* xs_buf   = mean_buf + BATCH * DMODEL;     // 8192
    float* sz_buf   = xs_buf + BATCH * DINNER;       // 8192
    float* yv_buf   = sz_buf + BATCH * DINNER;       // 8192

    mean_kernel<<<BATCH * DMODEL, 256, 0, stream>>>(x, mean_buf);
    k2a_win_kernel<<<2048, 256, 0, stream>>>(mean_buf, W_in, conv_w, conv_b,
                                             xs_buf, sz_buf);
    k2b_mid_kernel<<<BATCH, 512, 0, stream>>>(xs_buf, sz_buf, W_x, W_dt, b_dt,
                                              D_param, yv_buf);
    gate_mul_kernel<<<BATCH * DMODEL, 256, 0, stream>>>(x, yv_buf, W_out, out);
}